// Round 6
// baseline (119.938 us; speedup 1.0000x reference)
//
#include <hip/hip_runtime.h>

#define B_  16
#define N_  128
#define NF_ 128
#define H_  128

typedef __attribute__((ext_vector_type(8))) short short8;
typedef __attribute__((ext_vector_type(4))) float floatx4;

__device__ __forceinline__ float silu_f(float x) {
    return x / (1.0f + __expf(-x));
}
__device__ __forceinline__ float sigm_f(float x) {
    return 1.0f / (1.0f + __expf(-x));
}
__device__ __forceinline__ unsigned short f2bf(float x) {
    union { float f; unsigned u; } v; v.f = x;
    unsigned r = (v.u + 0x7FFFu + ((v.u >> 16) & 1u)) >> 16;
    return (unsigned short)r;
}
__device__ __forceinline__ float bf2f(unsigned short s) {
    union { unsigned u; float f; } v; v.u = ((unsigned)s) << 16;
    return v.f;
}

// ---------------- k1: per-node precompute A = nf@We1[0:128], Bm = nf@We1[128:256]
__global__ __launch_bounds__(128) void k1_pre(const float* __restrict__ nf,
                                              const float* __restrict__ We1,
                                              float* __restrict__ A_ws,
                                              float* __restrict__ Bm_ws) {
    const int b  = blockIdx.x >> 4;
    const int r0 = (blockIdx.x & 15) << 3;
    const int h  = threadIdx.x;
    __shared__ float rows[8][128];
#pragma unroll
    for (int r = 0; r < 8; ++r)
        rows[r][h] = nf[((size_t)(b * N_ + r0 + r)) * NF_ + h];
    __syncthreads();
    float a[8], bm[8];
#pragma unroll
    for (int r = 0; r < 8; ++r) { a[r] = 0.f; bm[r] = 0.f; }
    for (int c = 0; c < NF_; ++c) {
        const float w1 = We1[c * H_ + h];
        const float w2 = We1[(NF_ + c) * H_ + h];
#pragma unroll
        for (int r = 0; r < 8; ++r) {
            const float x = rows[r][c];
            a[r]  = fmaf(x, w1, a[r]);
            bm[r] = fmaf(x, w2, bm[r]);
        }
    }
#pragma unroll
    for (int r = 0; r < 8; ++r) {
        A_ws [((size_t)(b * N_ + r0 + r)) * H_ + h] = a[r];
        Bm_ws[((size_t)(b * N_ + r0 + r)) * H_ + h] = bm[r];
    }
}

// ---------------- kC: Cinv[b] = 1/(sum_j valid - 1)
__global__ __launch_bounds__(64) void kC(const float* __restrict__ valid,
                                         float* __restrict__ Cinv) {
    const int b = blockIdx.x;
    const int t = threadIdx.x;
    float v = valid[b * N_ + t] + valid[b * N_ + 64 + t];
#pragma unroll
    for (int m = 32; m >= 1; m >>= 1) v += __shfl_down(v, m, 64);
    if (t == 0) Cinv[b] = 1.0f / (v - 1.0f);
}

// ---------------- k2: fused edge pipeline ----------------
// LDS layout (bytes) — STATIC shared, 152128 B total (< 160 KiB)
#define SZ_BIG    (128 * 136 * 2)
#define OFF_BM    0
#define OFF_W2T   (OFF_BM + SZ_BIG)
#define OFF_WC1T  (OFF_W2T + SZ_BIG)
#define OFF_MBUF  (OFF_WC1T + SZ_BIG)
#define OFF_A     (OFF_MBUF + SZ_BIG)          // 8*128 f32
#define OFF_W256  (OFF_A + 8 * 128 * 4)
#define OFF_W257  (OFF_W256 + 512)
#define OFF_WC2   (OFF_W257 + 512)
#define OFF_WI    (OFF_WC2 + 512)
#define OFF_POSJ  (OFF_WI + 512)               // 128*3 f32
#define OFF_VALJ  (OFF_POSJ + 1536)
#define OFF_POSI  (OFF_VALJ + 512)             // 24 f32 (padded to 128B)
#define OFF_VALI  (OFF_POSI + 128)             // 8 f32 (padded to 64B)
#define OFF_MSGR  (OFF_VALI + 64)              // 8*128 f32
#define OFF_POSR  (OFF_MSGR + 4096)            // 32*3 f32
#define SMEM_K2   (OFF_POSR + 384)             // = 152128 bytes

__global__ __launch_bounds__(512, 1) void k2_edge(
        const float* __restrict__ pos,
        const float* __restrict__ valid,
        const float* __restrict__ adj,
        const float* __restrict__ We1,
        const float* __restrict__ We2,
        const float* __restrict__ Wc1,
        const float* __restrict__ Wc2,
        const float* __restrict__ Wi,
        const float* __restrict__ A_ws,
        const float* __restrict__ Bm_ws,
        const float* __restrict__ Cinv,
        float* __restrict__ msg_ws,
        float* __restrict__ pos_out) {
    __shared__ __align__(16) char smem[SMEM_K2];
    unsigned short* BM   = (unsigned short*)(smem + OFF_BM);
    unsigned short* W2T  = (unsigned short*)(smem + OFF_W2T);
    unsigned short* WC1T = (unsigned short*)(smem + OFF_WC1T);
    unsigned short* MB   = (unsigned short*)(smem + OFF_MBUF);
    float* A_s  = (float*)(smem + OFF_A);
    float* w256 = (float*)(smem + OFF_W256);
    float* w257 = (float*)(smem + OFF_W257);
    float* wc2s = (float*)(smem + OFF_WC2);
    float* wis  = (float*)(smem + OFF_WI);
    float* posj = (float*)(smem + OFF_POSJ);
    float* valj = (float*)(smem + OFF_VALJ);
    float* posi = (float*)(smem + OFF_POSI);
    float* vali = (float*)(smem + OFF_VALI);
    float* MSGR = (float*)(smem + OFF_MSGR);
    float* POSR = (float*)(smem + OFF_POSR);

    const int tid = threadIdx.x;
    const int b   = blockIdx.x >> 4;
    const int i0  = (blockIdx.x & 15) << 3;

    // ---- staging ----
    for (int q = tid; q < (N_ * H_) / 4; q += 512) {       // Bm -> bf16 LDS
        const int j  = q >> 5;
        const int ch = (q << 2) & 127;
        const float4 v = *(const float4*)(Bm_ws + ((size_t)(b * N_ + j)) * H_ + ch);
        ushort4 o;
        o.x = f2bf(v.x); o.y = f2bf(v.y); o.z = f2bf(v.z); o.w = f2bf(v.w);
        *(ushort4*)(BM + j * 136 + ch) = o;
    }
    for (int x = tid; x < H_ * H_; x += 512) {             // We2^T
        const int k = x >> 7, n = x & 127;
        W2T[n * 136 + k] = f2bf(We2[x]);
    }
    for (int x = tid; x < H_ * H_; x += 512) {             // Wc1^T
        const int k = x >> 7, n = x & 127;
        WC1T[n * 136 + k] = f2bf(Wc1[x]);
    }
    for (int x = tid; x < 8 * H_; x += 512)
        A_s[x] = A_ws[((size_t)(b * N_ + i0)) * H_ + x];
    if (tid < 128) {
        w256[tid] = We1[256 * H_ + tid];
        w257[tid] = We1[257 * H_ + tid];
        wc2s[tid] = Wc2[tid];
        wis[tid]  = Wi[tid];
        valj[tid] = valid[b * N_ + tid];
    }
    if (tid < 384)                     posj[tid] = pos[b * N_ * 3 + tid];
    if (tid >= 128 && tid < 128 + 24)  posi[tid - 128] = pos[b * N_ * 3 + i0 * 3 + (tid - 128)];
    if (tid >= 160 && tid < 168)       vali[tid - 160] = valid[b * N_ + i0 + (tid - 160)];
    __syncthreads();

    const int w  = tid >> 6;
    const int l  = tid & 63;
    const int lr = l & 15;
    const int lg = l >> 4;
    const int jj = (w << 4) + lr;          // this lane's j (A-fragment row)
    const float cinv = Cinv[b];
    const float vj   = valj[jj];
    const float pjx = posj[jj * 3 + 0], pjy = posj[jj * 3 + 1], pjz = posj[jj * 3 + 2];
    unsigned short* MBw = MB + w * (16 * 136);

    for (int p = 0; p < 8; ++p) {
        const int i = i0 + p;
        const float adjv = adj[((size_t)(b * N_ + i)) * N_ + jj];
        const float vx = posi[p * 3 + 0] - pjx;
        const float vy = posi[p * 3 + 1] - pjy;
        const float vz = posi[p * 3 + 2] - pjz;
        const float dist = vx * vx + vy * vy + vz * vz;
        const float vm   = vali[p] * vj;
        const float rn   = 1.0f / fmaxf(sqrtf(dist), 1e-10f);
        const float vnx = vx * rn, vny = vy * rn, vnz = vz * rn;

        // ---- GEMM1: silu(edge preact) @ We2 ----
        floatx4 acc1[8];
        const floatx4 zf = {0.f, 0.f, 0.f, 0.f};
#pragma unroll
        for (int nt = 0; nt < 8; ++nt) acc1[nt] = zf;
        const float* Arow = A_s + p * H_;
#pragma unroll
        for (int ks = 0; ks < 4; ++ks) {
            const int chb = ks * 32 + lg * 8;
            short8 af;
#pragma unroll
            for (int e = 0; e < 8; ++e) {
                const int ch = chb + e;
                const float pre = Arow[ch] + bf2f(BM[jj * 136 + ch])
                                + dist * w256[ch] + adjv * w257[ch];
                af[e] = (short)f2bf(silu_f(pre));
            }
#pragma unroll
            for (int nt = 0; nt < 8; ++nt) {
                const short8 bf = *(const short8*)(W2T + (nt * 16 + lr) * 136 + chb);
                acc1[nt] = __builtin_amdgcn_mfma_f32_16x16x32_bf16(af, bf, acc1[nt], 0, 0, 0);
            }
        }
        // m = silu(.)  (D layout: lane holds edge rhat=lg*4+r, channel h=nt*16+lr)
        float m[8][4];
#pragma unroll
        for (int nt = 0; nt < 8; ++nt)
#pragma unroll
            for (int r = 0; r < 4; ++r)
                m[nt][r] = silu_f(acc1[nt][r]);

        // e gate: sigmoid(m @ Wi)
        float ep0 = 0.f, ep1 = 0.f, ep2 = 0.f, ep3 = 0.f;
#pragma unroll
        for (int nt = 0; nt < 8; ++nt) {
            const float wv = wis[nt * 16 + lr];
            ep0 = fmaf(m[nt][0], wv, ep0);
            ep1 = fmaf(m[nt][1], wv, ep1);
            ep2 = fmaf(m[nt][2], wv, ep2);
            ep3 = fmaf(m[nt][3], wv, ep3);
        }
#pragma unroll
        for (int msk = 1; msk < 16; msk <<= 1) {
            ep0 += __shfl_xor(ep0, msk, 64);
            ep1 += __shfl_xor(ep1, msk, 64);
            ep2 += __shfl_xor(ep2, msk, 64);
            ep3 += __shfl_xor(ep3, msk, 64);
        }
        const float eg[4] = { sigm_f(ep0), sigm_f(ep1), sigm_f(ep2), sigm_f(ep3) };

        // bring per-edge scalars into D layout (edge rhat = lg*4+r)
        float adj_r[4], vm_r[4], vnx_r[4], vny_r[4], vnz_r[4];
#pragma unroll
        for (int r = 0; r < 4; ++r) {
            const int src = (l & 48) | ((lg << 2) + r);
            adj_r[r] = __shfl(adjv, src, 64);
            vm_r[r]  = __shfl(vm,   src, 64);
            vnx_r[r] = __shfl(vnx,  src, 64);
            vny_r[r] = __shfl(vny,  src, 64);
            vnz_r[r] = __shfl(vnz,  src, 64);
        }

        // stash ungated m (bf16) for GEMM2 re-fragmentation
#pragma unroll
        for (int nt = 0; nt < 8; ++nt)
#pragma unroll
            for (int r = 0; r < 4; ++r)
                MBw[((lg << 2) + r) * 136 + nt * 16 + lr] = f2bf(m[nt][r]);

        // message partial: sum_j m*e*adj
#pragma unroll
        for (int nt = 0; nt < 8; ++nt) {
            float s = m[nt][0] * eg[0] * adj_r[0]
                    + m[nt][1] * eg[1] * adj_r[1]
                    + m[nt][2] * eg[2] * adj_r[2]
                    + m[nt][3] * eg[3] * adj_r[3];
            s += __shfl_xor(s, 16, 64);
            s += __shfl_xor(s, 32, 64);
            if (l < 16) MSGR[w * 128 + nt * 16 + l] = s;
        }

        // ---- GEMM2: m @ Wc1 ----
        floatx4 acc2[8];
#pragma unroll
        for (int nt = 0; nt < 8; ++nt) acc2[nt] = zf;
#pragma unroll
        for (int ks = 0; ks < 4; ++ks) {
            const int chb = ks * 32 + lg * 8;
            const short8 a2 = *(const short8*)(MBw + lr * 136 + chb);
#pragma unroll
            for (int nt = 0; nt < 8; ++nt) {
                const short8 bf = *(const short8*)(WC1T + (nt * 16 + lr) * 136 + chb);
                acc2[nt] = __builtin_amdgcn_mfma_f32_16x16x32_bf16(a2, bf, acc2[nt], 0, 0, 0);
            }
        }
        // phi = silu(.) @ Wc2
        float ph0 = 0.f, ph1 = 0.f, ph2 = 0.f, ph3 = 0.f;
#pragma unroll
        for (int nt = 0; nt < 8; ++nt) {
            const float wv = wc2s[nt * 16 + lr];
            ph0 = fmaf(silu_f(acc2[nt][0]), wv, ph0);
            ph1 = fmaf(silu_f(acc2[nt][1]), wv, ph1);
            ph2 = fmaf(silu_f(acc2[nt][2]), wv, ph2);
            ph3 = fmaf(silu_f(acc2[nt][3]), wv, ph3);
        }
#pragma unroll
        for (int msk = 1; msk < 16; msk <<= 1) {
            ph0 += __shfl_xor(ph0, msk, 64);
            ph1 += __shfl_xor(ph1, msk, 64);
            ph2 += __shfl_xor(ph2, msk, 64);
            ph3 += __shfl_xor(ph3, msk, 64);
        }
        if (lr == 0) {
            const float t0 = ph0 * vm_r[0], t1 = ph1 * vm_r[1],
                        t2 = ph2 * vm_r[2], t3 = ph3 * vm_r[3];
            const int row = (w << 2) + lg;
            POSR[row * 3 + 0] = vnx_r[0]*t0 + vnx_r[1]*t1 + vnx_r[2]*t2 + vnx_r[3]*t3;
            POSR[row * 3 + 1] = vny_r[0]*t0 + vny_r[1]*t1 + vny_r[2]*t2 + vny_r[3]*t3;
            POSR[row * 3 + 2] = vnz_r[0]*t0 + vnz_r[1]*t1 + vnz_r[2]*t2 + vnz_r[3]*t3;
        }
        __syncthreads();
        if (tid < 128) {
            float s = 0.f;
#pragma unroll
            for (int ww = 0; ww < 8; ++ww) s += MSGR[ww * 128 + tid];
            msg_ws[((size_t)(b * N_ + i)) * H_ + tid] = s;
        } else if (tid < 131) {
            const int c = tid - 128;
            float s = 0.f;
#pragma unroll
            for (int q = 0; q < 32; ++q) s += POSR[q * 3 + c];
            pos_out[((size_t)(b * N_ + i)) * 3 + c] =
                pos[((size_t)(b * N_ + i)) * 3 + c] + cinv * s;
        }
        __syncthreads();
    }
}

// ---------------- k3: node MLP ----------------
__global__ __launch_bounds__(128) void k3_node(
        const float* __restrict__ nf,
        const float* __restrict__ Wn1,
        const float* __restrict__ Wn2,
        const float* __restrict__ msg_ws,
        float* __restrict__ out) {
    const int b  = blockIdx.x >> 4;
    const int r0 = (blockIdx.x & 15) << 3;
    const int h  = threadIdx.x;
    __shared__ float in_s[8][256];
    __shared__ float t_s[8][128];
#pragma unroll
    for (int r = 0; r < 8; ++r) {
        in_s[r][h]       = nf[((size_t)(b * N_ + r0 + r)) * NF_ + h];
        in_s[r][128 + h] = msg_ws[((size_t)(b * N_ + r0 + r)) * H_ + h];
    }
    __syncthreads();
    float acc[8];
#pragma unroll
    for (int r = 0; r < 8; ++r) acc[r] = 0.f;
    for (int c = 0; c < 256; ++c) {
        const float wv = Wn1[c * H_ + h];
#pragma unroll
        for (int r = 0; r < 8; ++r) acc[r] = fmaf(in_s[r][c], wv, acc[r]);
    }
#pragma unroll
    for (int r = 0; r < 8; ++r) t_s[r][h] = silu_f(acc[r]);
    __syncthreads();
    float o[8];
#pragma unroll
    for (int r = 0; r < 8; ++r) o[r] = 0.f;
    for (int c = 0; c < 128; ++c) {
        const float wv = Wn2[c * NF_ + h];
#pragma unroll
        for (int r = 0; r < 8; ++r) o[r] = fmaf(t_s[r][c], wv, o[r]);
    }
#pragma unroll
    for (int r = 0; r < 8; ++r)
        out[((size_t)(b * N_ + r0 + r)) * NF_ + h] = in_s[r][h] + o[r];
}

extern "C" void kernel_launch(void* const* d_in, const int* in_sizes, int n_in,
                              void* d_out, int out_size, void* d_ws, size_t ws_size,
                              hipStream_t stream) {
    const float* node_feat = (const float*)d_in[0];
    const float* pos   = (const float*)d_in[1];
    const float* valid = (const float*)d_in[2];
    const float* adj   = (const float*)d_in[3];
    const float* We1   = (const float*)d_in[4];
    const float* We2   = (const float*)d_in[5];
    const float* Wc1   = (const float*)d_in[6];
    const float* Wc2   = (const float*)d_in[7];
    const float* Wn1   = (const float*)d_in[8];
    const float* Wn2   = (const float*)d_in[9];
    const float* Wi    = (const float*)d_in[10];

    float* out     = (float*)d_out;
    float* pos_out = out + (size_t)B_ * N_ * NF_;

    const size_t node_elems = (size_t)B_ * N_ * H_;
    if (ws_size < (3 * node_elems + B_) * sizeof(float)) return;
    float* A_ws   = (float*)d_ws;
    float* Bm_ws  = A_ws + node_elems;
    float* msg_ws = Bm_ws + node_elems;
    float* Cinv   = msg_ws + node_elems;

    k1_pre<<<B_ * 16, 128, 0, stream>>>(node_feat, We1, A_ws, Bm_ws);
    kC<<<B_, 64, 0, stream>>>(valid, Cinv);
    k2_edge<<<B_ * 16, 512, 0, stream>>>(pos, valid, adj, We1, We2, Wc1, Wc2, Wi,
                                         A_ws, Bm_ws, Cinv, msg_ws, pos_out);
    k3_node<<<B_ * 16, 128, 0, stream>>>(node_feat, Wn1, Wn2, msg_ws, out);
}